// Round 18
// baseline (510.721 us; speedup 1.0000x reference)
//
#include <hip/hip_runtime.h>
#include <math.h>

#define N_    16
#define CIN_  16
#define T_    512
#define V_    200
#define K_    3
#define COUT_ 64
#define H_    64
#define G_    256  // 4*H

// Workspace layout (float offsets):
//   a  : [0, 600)                 a[k][v] = sum_w A[k,v,w] / V
//   sa : [640, 643)               sa[k] = sum_{v,w} A[k,v,w] / V
//   xa : [1024, 1024+16*512*48)   xa[n][t][k*16+ci]
//   xW : [WS_XW, +512*16*256)     xW[t][n][g]  (gate pre-activations, input side)
#define WS_A  0
#define WS_SA 640
#define WS_XA 1024
#define WS_XW (WS_XA + N_ * T_ * K_ * CIN_)

typedef __attribute__((ext_vector_type(4))) float f32x4;

// fast activations: v_exp_f32-based, ~1e-6 rel err, saturate correctly
__device__ __forceinline__ float fast_sig(float x) {
    return __builtin_amdgcn_rcpf(1.f + __expf(-x));
}
__device__ __forceinline__ float fast_tanh(float x) {
    return fmaf(-2.f, __builtin_amdgcn_rcpf(1.f + __expf(2.f * x)), 1.f);
}

// ---------------------------------------------------------------------------
// Kernel 1 (fused prep): blocks [0, NCOPY) copy A->out[16:] (blocks 0-2 also
// compute a[k][v]); blocks NCOPY+k (k=0..2) reduce A[k] to sa[k].
#define NCOPY ((K_ * V_ * V_ + 255) / 256)
__global__ __launch_bounds__(256) void prep_kernel(const float* __restrict__ A,
                                                   float* __restrict__ out,
                                                   float* __restrict__ ws) {
    int b = blockIdx.x;
    if (b < NCOPY) {
        int tid = b * 256 + threadIdx.x;
        if (tid < K_ * V_ * V_) out[16 + tid] = A[tid];
        if (tid < K_ * V_) {
            const float* row = A + (long)tid * V_;
            float s = 0.f;
            for (int w = 0; w < V_; ++w) s += row[w];
            ws[WS_A + tid] = s * (1.0f / V_);
        }
    } else {
        int k = b - NCOPY;                      // 0..2
        const float* Ak = A + (long)k * V_ * V_;
        float s = 0.f;
        for (int i = threadIdx.x; i < V_ * V_; i += 256) s += Ak[i];
        #pragma unroll
        for (int m = 1; m < 64; m <<= 1) s += __shfl_xor(s, m);
        __shared__ float red[4];
        if ((threadIdx.x & 63) == 0) red[threadIdx.x >> 6] = s;
        __syncthreads();
        if (threadIdx.x == 0)
            ws[WS_SA + k] = (red[0] + red[1] + red[2] + red[3]) * (1.0f / V_);
    }
}

// ---------------------------------------------------------------------------
// Kernel 2 (tiled xa): xa[n][t][k*16+ci] = sum_v x[n][ci][t][v] * a[k][v]
// One block per (n, ci, 64-t chunk) = 2048 blocks.
#define TT 64
#define PADV 204
__global__ __launch_bounds__(256) void xa_kernel(const float* __restrict__ x,
                                                 float* __restrict__ ws) {
    __shared__ __align__(16) float xt[TT * PADV];
    __shared__ __align__(16) float aS[K_ * V_];
    int tid = threadIdx.x;
    int b = blockIdx.x;
    int tchunk = b & 7;
    int ci = (b >> 3) & 15;
    int n = b >> 7;
    int t0 = tchunk * TT;

    for (int i = tid; i < K_ * V_; i += 256) aS[i] = ws[WS_A + i];

    const float4* xg4 =
        (const float4*)(x + ((long)(n * CIN_ + ci) * T_ + t0) * V_);
    for (int j = tid; j < TT * (V_ / 4); j += 256) {
        float4 v = xg4[j];
        int t = j / (V_ / 4), v4 = (j % (V_ / 4)) * 4;
        *(float4*)(xt + t * PADV + v4) = v;
    }
    __syncthreads();

    int t_local = tid & 63;
    int k = tid >> 6;            // waves 0..2 active, wave 3 idle
    if (k < K_) {
        const float* xr = xt + t_local * PADV;
        const float* ar = aS + k * V_;
        float a0 = 0.f, a1 = 0.f, a2 = 0.f, a3 = 0.f;
        #pragma unroll 5
        for (int v4 = 0; v4 < V_; v4 += 4) {
            float4 xv = *(const float4*)(xr + v4);
            float4 av = *(const float4*)(ar + v4);   // wave-uniform broadcast
            a0 = fmaf(xv.x, av.x, a0);
            a1 = fmaf(xv.y, av.y, a1);
            a2 = fmaf(xv.z, av.z, a2);
            a3 = fmaf(xv.w, av.w, a3);
        }
        float s = (a0 + a1) + (a2 + a3);
        ws[WS_XA + ((long)n * T_ + (t0 + t_local)) * (K_ * CIN_) + k * CIN_ + ci] = s;
    }
}

// ---------------------------------------------------------------------------
// Kernel 3 (fused seq + input-gate GEMM): ONE block per t (512 blocks).
__global__ __launch_bounds__(256) void seqgates_kernel(
    const float* __restrict__ W_gcn, const float* __restrict__ b_gcn,
    const float* __restrict__ W_ih, const float* __restrict__ b_ih,
    const float* __restrict__ b_hh, float* __restrict__ ws) {
    int t = blockIdx.x;
    int tid = threadIdx.x;
    __shared__ float xaS[N_][K_ * CIN_];
    __shared__ __align__(16) float seqS[N_][COUT_];
    __shared__ float saS[K_];

    if (tid < K_) saS[tid] = ws[WS_SA + tid];
    #pragma unroll
    for (int r = 0; r < 3; ++r) {
        int i = tid + r * 256;
        if (i < N_ * K_ * CIN_) {
            int n = i / (K_ * CIN_), kc = i % (K_ * CIN_);
            xaS[n][kc] = ws[WS_XA + (long)(n * T_ + t) * (K_ * CIN_) + kc];
        }
    }
    __syncthreads();

    // Phase 1: thread (n = tid>>4, c0 = (tid&15)*4) computes 4 seq entries.
    {
        int n = tid >> 4, c0 = (tid & 15) * 4;
        #pragma unroll
        for (int cc = 0; cc < 4; ++cc) {
            int c = c0 + cc;
            float s = 0.f;
            #pragma unroll
            for (int k = 0; k < K_; ++k) {
                s = fmaf(b_gcn[k * COUT_ + c], saS[k], s);
                const float* wrow = W_gcn + (long)(k * COUT_ + c) * CIN_;
                #pragma unroll
                for (int ci = 0; ci < CIN_; ++ci)
                    s = fmaf(wrow[ci], xaS[n][k * CIN_ + ci], s);
            }
            seqS[n][c] = s;
        }
    }
    __syncthreads();

    // Phase 2: thread g: 16 accumulators over n; W_ih row streamed as float4.
    {
        int g = tid;
        float acc[N_];
        #pragma unroll
        for (int n = 0; n < N_; ++n) acc[n] = 0.f;
        const float4* wrow4 = (const float4*)(W_ih + (long)g * H_);
        #pragma unroll
        for (int c4 = 0; c4 < H_ / 4; ++c4) {
            float4 w4 = wrow4[c4];
            #pragma unroll
            for (int n = 0; n < N_; ++n) {
                float4 s4 = ((const float4*)seqS[n])[c4];  // LDS broadcast
                acc[n] = fmaf(w4.x, s4.x, acc[n]);
                acc[n] = fmaf(w4.y, s4.y, acc[n]);
                acc[n] = fmaf(w4.z, s4.z, acc[n]);
                acc[n] = fmaf(w4.w, s4.w, acc[n]);
            }
        }
        float bias = b_ih[g] + b_hh[g];
        #pragma unroll
        for (int n = 0; n < N_; ++n)
            ws[WS_XW + (long)(t * N_ + n) * G_ + g] = acc[n] + bias;
    }
}

// ---------------------------------------------------------------------------
// Kernel 4: sequential LSTM scan — ONE WAVE per batch, ZERO sync.
// Ledger R12-R17: the 4-wave structure is the invariant cost (barriers +
// shared DS pipe + split activation path); weight residency alone moved
// nothing. Here lane j holds ALL FOUR gate rows of its j (256 VGPRs,
// resident via asm WLOAD + waves_per_eu(1,1), proven R16) and computes all
// 4 dots; i/f/g/o are lane-local -> no gbuf, no shuffles, NO BARRIERS.
// h exchange = 1 ds_write + 16 uniform ds_read_b128, ordered by the wave's
// in-order DS pipe. 16 blocks x 64 threads.
__global__ __attribute__((amdgpu_waves_per_eu(1, 1)))
__launch_bounds__(64) void lstm_kernel(
    const float* __restrict__ W_hh, const float* __restrict__ W_fc,
    const float* __restrict__ b_fc, const float* __restrict__ ws,
    float* __restrict__ out) {
    int n = blockIdx.x;
    int j = threadIdx.x;          // hidden index 0..63

    // Resident load of rows j, 64+j, 128+j, 192+j (torch gate order i,f,g,o).
    const f32x4* ra = (const f32x4*)(W_hh + (long)(0 * H_ + j) * H_);
    const f32x4* rb = (const f32x4*)(W_hh + (long)(1 * H_ + j) * H_);
    const f32x4* rc = (const f32x4*)(W_hh + (long)(2 * H_ + j) * H_);
    const f32x4* rd = (const f32x4*)(W_hh + (long)(3 * H_ + j) * H_);
    f32x4 wa0, wa1, wa2, wa3, wa4, wa5, wa6, wa7, wa8, wa9, wa10, wa11, wa12, wa13, wa14, wa15;
    f32x4 wb0, wb1, wb2, wb3, wb4, wb5, wb6, wb7, wb8, wb9, wb10, wb11, wb12, wb13, wb14, wb15;
    f32x4 wc0, wc1, wc2, wc3, wc4, wc5, wc6, wc7, wc8, wc9, wc10, wc11, wc12, wc13, wc14, wc15;
    f32x4 wd0, wd1, wd2, wd3, wd4, wd5, wd6, wd7, wd8, wd9, wd10, wd11, wd12, wd13, wd14, wd15;
    #define WLOAD(dst, src, i) \
        asm volatile("global_load_dwordx4 %0, %1, off" : "=v"(dst##i) : "v"(src + i));
    #define WLOAD16(dst, src) \
        WLOAD(dst, src, 0)  WLOAD(dst, src, 1)  WLOAD(dst, src, 2)  WLOAD(dst, src, 3)  \
        WLOAD(dst, src, 4)  WLOAD(dst, src, 5)  WLOAD(dst, src, 6)  WLOAD(dst, src, 7)  \
        WLOAD(dst, src, 8)  WLOAD(dst, src, 9)  WLOAD(dst, src, 10) WLOAD(dst, src, 11) \
        WLOAD(dst, src, 12) WLOAD(dst, src, 13) WLOAD(dst, src, 14) WLOAD(dst, src, 15)
    WLOAD16(wa, ra)
    WLOAD16(wb, rb)
    WLOAD16(wc, rc)
    WLOAD16(wd, rd)
    #undef WLOAD16
    #undef WLOAD
    asm volatile("s_waitcnt vmcnt(0)" ::: "memory");

    __shared__ __align__(16) float hS[2][H_];
    hS[0][j] = 0.f;
    float ccell = 0.f;

    const float* xw = ws + WS_XW + (long)n * G_ + j;
    // per-type pre-activations (stride 64 in g), depth-2 prefetch
    float xc0 = xw[0],   xc1 = xw[64],  xc2 = xw[128], xc3 = xw[192];
    const float* xw1 = xw + (long)N_ * G_;
    float xn0 = xw1[0],  xn1 = xw1[64], xn2 = xw1[128], xn3 = xw1[192];

    for (int t = 0; t < T_; ++t) {
        int p = t & 1;
        // 4 dots x 64, 16 ILP chains; h via uniform-address b128 broadcasts
        float a0 = 0.f, a1 = 0.f, a2 = 0.f, a3 = 0.f;
        float b0 = 0.f, b1 = 0.f, b2 = 0.f, b3 = 0.f;
        float c0 = 0.f, c1 = 0.f, c2 = 0.f, c3 = 0.f;
        float d0 = 0.f, d1 = 0.f, d2 = 0.f, d3 = 0.f;
        const float4* h4 = (const float4*)hS[p];
        #define DOT16(i)                           \
            {                                      \
                float4 hv = h4[i];                 \
                a0 = fmaf(wa##i[0], hv.x, a0);     \
                a1 = fmaf(wa##i[1], hv.y, a1);     \
                a2 = fmaf(wa##i[2], hv.z, a2);     \
                a3 = fmaf(wa##i[3], hv.w, a3);     \
                b0 = fmaf(wb##i[0], hv.x, b0);     \
                b1 = fmaf(wb##i[1], hv.y, b1);     \
                b2 = fmaf(wb##i[2], hv.z, b2);     \
                b3 = fmaf(wb##i[3], hv.w, b3);     \
                c0 = fmaf(wc##i[0], hv.x, c0);     \
                c1 = fmaf(wc##i[1], hv.y, c1);     \
                c2 = fmaf(wc##i[2], hv.z, c2);     \
                c3 = fmaf(wc##i[3], hv.w, c3);     \
                d0 = fmaf(wd##i[0], hv.x, d0);     \
                d1 = fmaf(wd##i[1], hv.y, d1);     \
                d2 = fmaf(wd##i[2], hv.z, d2);     \
                d3 = fmaf(wd##i[3], hv.w, d3);     \
            }
        DOT16(0)  DOT16(1)  DOT16(2)  DOT16(3)
        DOT16(4)  DOT16(5)  DOT16(6)  DOT16(7)
        DOT16(8)  DOT16(9)  DOT16(10) DOT16(11)
        DOT16(12) DOT16(13) DOT16(14) DOT16(15)
        #undef DOT16

        float gi = xc0 + (a0 + a1) + (a2 + a3);
        float gf = xc1 + (b0 + b1) + (b2 + b3);
        float gg = xc2 + (c0 + c1) + (c2 + c3);
        float go = xc3 + (d0 + d1) + (d2 + d3);

        xc0 = xn0; xc1 = xn1; xc2 = xn2; xc3 = xn3;
        if (t + 2 < T_) {
            const float* xw2 = xw + (long)(t + 2) * N_ * G_;
            xn0 = xw2[0]; xn1 = xw2[64]; xn2 = xw2[128]; xn3 = xw2[192];
        }

        // all gate types lane-local: no exchange at all
        float iv = fast_sig(gi);
        float fv = fast_sig(gf);
        float gv = fast_tanh(gg);
        float ov = fast_sig(go);
        ccell = fmaf(fv, ccell, iv * gv);
        float h = ov * fast_tanh(ccell);
        hS[p ^ 1][j] = h;   // same-wave DS pipe is in-order: no barrier needed
    }

    // final: out[n] = dot(h, W_fc) + b_fc (h of own j is in-register)
    {
        float h = hS[0][j];   // T_ even -> final h in hS[0]
        float pv = h * W_fc[j];
        #pragma unroll
        for (int m = 1; m < 64; m <<= 1) pv += __shfl_xor(pv, m);
        if (j == 0) out[n] = pv + b_fc[0];
    }
}

// ---------------------------------------------------------------------------
extern "C" void kernel_launch(void* const* d_in, const int* in_sizes, int n_in,
                              void* d_out, int out_size, void* d_ws, size_t ws_size,
                              hipStream_t stream) {
    const float* x     = (const float*)d_in[0];
    const float* A     = (const float*)d_in[1];
    const float* W_gcn = (const float*)d_in[2];
    const float* b_gcn = (const float*)d_in[3];
    const float* W_ih  = (const float*)d_in[4];
    const float* W_hh  = (const float*)d_in[5];
    const float* b_ih  = (const float*)d_in[6];
    const float* b_hh  = (const float*)d_in[7];
    const float* W_fc  = (const float*)d_in[8];
    const float* b_fc  = (const float*)d_in[9];
    float* out = (float*)d_out;
    float* ws  = (float*)d_ws;

    // 1) fused: copy A->out, a[k][v], sa[k]
    prep_kernel<<<NCOPY + K_, 256, 0, stream>>>(A, out, ws);
    // 2) tiled xa (one block per (n, ci, 64-t chunk))
    xa_kernel<<<N_ * CIN_ * (T_ / TT), 256, 0, stream>>>(x, ws);
    // 3) fused seq + input-side gate GEMM (one block per t)
    seqgates_kernel<<<T_, 256, 0, stream>>>(W_gcn, b_gcn, W_ih, b_ih, b_hh, ws);
    // 4) single-wave, zero-sync sequential LSTM scan + final FC
    lstm_kernel<<<N_, 64, 0, stream>>>(W_hh, W_fc, b_fc, ws, out);
}

// Round 19
// 349.732 us; speedup vs baseline: 1.4603x; 1.4603x over previous
//
#include <hip/hip_runtime.h>
#include <math.h>

#define N_    16
#define CIN_  16
#define T_    512
#define V_    200
#define K_    3
#define COUT_ 64
#define H_    64
#define G_    256  // 4*H

// Workspace layout (float offsets):
//   a  : [0, 600)                 a[k][v] = sum_w A[k,v,w] / V
//   sa : [640, 643)               sa[k] = sum_{v,w} A[k,v,w] / V
//   xa : [1024, 1024+16*512*48)   xa[n][t][k*16+ci]
//   xW : [WS_XW, +512*16*256)     xW[t][n][g]  (gate pre-activations, input side)
#define WS_A  0
#define WS_SA 640
#define WS_XA 1024
#define WS_XW (WS_XA + N_ * T_ * K_ * CIN_)

typedef __attribute__((ext_vector_type(4))) float f32x4;

// fast activations: v_exp_f32-based, ~1e-6 rel err, saturate correctly
__device__ __forceinline__ float fast_sig(float x) {
    return __builtin_amdgcn_rcpf(1.f + __expf(-x));
}
__device__ __forceinline__ float fast_tanh(float x) {
    return fmaf(-2.f, __builtin_amdgcn_rcpf(1.f + __expf(2.f * x)), 1.f);
}

// ---------------------------------------------------------------------------
// Kernel 1 (fused prep): blocks [0, NCOPY) copy A->out[16:] (blocks 0-2 also
// compute a[k][v]); blocks NCOPY+k (k=0..2) reduce A[k] to sa[k].
#define NCOPY ((K_ * V_ * V_ + 255) / 256)
__global__ __launch_bounds__(256) void prep_kernel(const float* __restrict__ A,
                                                   float* __restrict__ out,
                                                   float* __restrict__ ws) {
    int b = blockIdx.x;
    if (b < NCOPY) {
        int tid = b * 256 + threadIdx.x;
        if (tid < K_ * V_ * V_) out[16 + tid] = A[tid];
        if (tid < K_ * V_) {
            const float* row = A + (long)tid * V_;
            float s = 0.f;
            for (int w = 0; w < V_; ++w) s += row[w];
            ws[WS_A + tid] = s * (1.0f / V_);
        }
    } else {
        int k = b - NCOPY;                      // 0..2
        const float* Ak = A + (long)k * V_ * V_;
        float s = 0.f;
        for (int i = threadIdx.x; i < V_ * V_; i += 256) s += Ak[i];
        #pragma unroll
        for (int m = 1; m < 64; m <<= 1) s += __shfl_xor(s, m);
        __shared__ float red[4];
        if ((threadIdx.x & 63) == 0) red[threadIdx.x >> 6] = s;
        __syncthreads();
        if (threadIdx.x == 0)
            ws[WS_SA + k] = (red[0] + red[1] + red[2] + red[3]) * (1.0f / V_);
    }
}

// ---------------------------------------------------------------------------
// Kernel 2 (tiled xa): xa[n][t][k*16+ci] = sum_v x[n][ci][t][v] * a[k][v]
// One block per (n, ci, 64-t chunk) = 2048 blocks.
#define TT 64
#define PADV 204
__global__ __launch_bounds__(256) void xa_kernel(const float* __restrict__ x,
                                                 float* __restrict__ ws) {
    __shared__ __align__(16) float xt[TT * PADV];
    __shared__ __align__(16) float aS[K_ * V_];
    int tid = threadIdx.x;
    int b = blockIdx.x;
    int tchunk = b & 7;
    int ci = (b >> 3) & 15;
    int n = b >> 7;
    int t0 = tchunk * TT;

    for (int i = tid; i < K_ * V_; i += 256) aS[i] = ws[WS_A + i];

    const float4* xg4 =
        (const float4*)(x + ((long)(n * CIN_ + ci) * T_ + t0) * V_);
    for (int j = tid; j < TT * (V_ / 4); j += 256) {
        float4 v = xg4[j];
        int t = j / (V_ / 4), v4 = (j % (V_ / 4)) * 4;
        *(float4*)(xt + t * PADV + v4) = v;
    }
    __syncthreads();

    int t_local = tid & 63;
    int k = tid >> 6;            // waves 0..2 active, wave 3 idle
    if (k < K_) {
        const float* xr = xt + t_local * PADV;
        const float* ar = aS + k * V_;
        float a0 = 0.f, a1 = 0.f, a2 = 0.f, a3 = 0.f;
        #pragma unroll 5
        for (int v4 = 0; v4 < V_; v4 += 4) {
            float4 xv = *(const float4*)(xr + v4);
            float4 av = *(const float4*)(ar + v4);   // wave-uniform broadcast
            a0 = fmaf(xv.x, av.x, a0);
            a1 = fmaf(xv.y, av.y, a1);
            a2 = fmaf(xv.z, av.z, a2);
            a3 = fmaf(xv.w, av.w, a3);
        }
        float s = (a0 + a1) + (a2 + a3);
        ws[WS_XA + ((long)n * T_ + (t0 + t_local)) * (K_ * CIN_) + k * CIN_ + ci] = s;
    }
}

// ---------------------------------------------------------------------------
// Kernel 3 (fused seq + input-gate GEMM): ONE block per t (512 blocks).
__global__ __launch_bounds__(256) void seqgates_kernel(
    const float* __restrict__ W_gcn, const float* __restrict__ b_gcn,
    const float* __restrict__ W_ih, const float* __restrict__ b_ih,
    const float* __restrict__ b_hh, float* __restrict__ ws) {
    int t = blockIdx.x;
    int tid = threadIdx.x;
    __shared__ float xaS[N_][K_ * CIN_];
    __shared__ __align__(16) float seqS[N_][COUT_];
    __shared__ float saS[K_];

    if (tid < K_) saS[tid] = ws[WS_SA + tid];
    #pragma unroll
    for (int r = 0; r < 3; ++r) {
        int i = tid + r * 256;
        if (i < N_ * K_ * CIN_) {
            int n = i / (K_ * CIN_), kc = i % (K_ * CIN_);
            xaS[n][kc] = ws[WS_XA + (long)(n * T_ + t) * (K_ * CIN_) + kc];
        }
    }
    __syncthreads();

    // Phase 1: thread (n = tid>>4, c0 = (tid&15)*4) computes 4 seq entries.
    {
        int n = tid >> 4, c0 = (tid & 15) * 4;
        #pragma unroll
        for (int cc = 0; cc < 4; ++cc) {
            int c = c0 + cc;
            float s = 0.f;
            #pragma unroll
            for (int k = 0; k < K_; ++k) {
                s = fmaf(b_gcn[k * COUT_ + c], saS[k], s);
                const float* wrow = W_gcn + (long)(k * COUT_ + c) * CIN_;
                #pragma unroll
                for (int ci = 0; ci < CIN_; ++ci)
                    s = fmaf(wrow[ci], xaS[n][k * CIN_ + ci], s);
            }
            seqS[n][c] = s;
        }
    }
    __syncthreads();

    // Phase 2: thread g: 16 accumulators over n; W_ih row streamed as float4.
    {
        int g = tid;
        float acc[N_];
        #pragma unroll
        for (int n = 0; n < N_; ++n) acc[n] = 0.f;
        const float4* wrow4 = (const float4*)(W_ih + (long)g * H_);
        #pragma unroll
        for (int c4 = 0; c4 < H_ / 4; ++c4) {
            float4 w4 = wrow4[c4];
            #pragma unroll
            for (int n = 0; n < N_; ++n) {
                float4 s4 = ((const float4*)seqS[n])[c4];  // LDS broadcast
                acc[n] = fmaf(w4.x, s4.x, acc[n]);
                acc[n] = fmaf(w4.y, s4.y, acc[n]);
                acc[n] = fmaf(w4.z, s4.z, acc[n]);
                acc[n] = fmaf(w4.w, s4.w, acc[n]);
            }
        }
        float bias = b_ih[g] + b_hh[g];
        #pragma unroll
        for (int n = 0; n < N_; ++n)
            ws[WS_XW + (long)(t * N_ + n) * G_ + g] = acc[n] + bias;
    }
}

// ---------------------------------------------------------------------------
// Kernel 4: sequential LSTM scan — R16 verbatim, the measured optimum over
// twelve structural variants (R3-R18): 4 waves, 2 barriers, gbuf exchange,
// weights VGPR-resident via asm WLOAD + amdgpu_waves_per_eu(1,1) (VGPR=132).
// Per-step cost is the irreducible serial chain {h-LDS roundtrip -> 64-dot
// -> sync -> activation chain} at the reduced clock of a 6%-occupied GPU;
// insensitive to weight tier, barrier count, exchange mechanism, wave count.
__global__ __attribute__((amdgpu_waves_per_eu(1, 1)))
__launch_bounds__(256) void lstm_kernel(
    const float* __restrict__ W_hh, const float* __restrict__ W_fc,
    const float* __restrict__ b_fc, const float* __restrict__ ws,
    float* __restrict__ out) {
    int n = blockIdx.x;
    int w = threadIdx.x >> 6;     // gate type (torch order: i,f,g,o)
    int lane = threadIdx.x & 63;  // gate index / h index

    // One-time, non-rematerializable load of this thread's W_hh row.
    const f32x4* wr = (const f32x4*)(W_hh + (long)(w * H_ + lane) * H_);
    f32x4 w0, w1, w2, w3, w4, w5, w6, w7, w8, w9, w10, w11, w12, w13, w14, w15;
    #define WLOAD(i) \
        asm volatile("global_load_dwordx4 %0, %1, off" : "=v"(w##i) : "v"(wr + i));
    WLOAD(0)  WLOAD(1)  WLOAD(2)  WLOAD(3)
    WLOAD(4)  WLOAD(5)  WLOAD(6)  WLOAD(7)
    WLOAD(8)  WLOAD(9)  WLOAD(10) WLOAD(11)
    WLOAD(12) WLOAD(13) WLOAD(14) WLOAD(15)
    #undef WLOAD
    asm volatile("s_waitcnt vmcnt(0)" ::: "memory");

    __shared__ __align__(16) float hS[H_];
    __shared__ float gbuf[4][H_];

    if (threadIdx.x < H_) hS[threadIdx.x] = 0.f;
    float ccell = 0.f, hlast = 0.f;   // live only in wave 0
    __syncthreads();

    const float* xw = ws + WS_XW + (long)n * G_ + (w * H_ + lane);
    float x0 = xw[0];
    float x1 = xw[(long)N_ * G_];

    for (int t = 0; t < T_; ++t) {
        float gate = x0;
        x0 = x1;
        if (t + 2 < T_) x1 = xw[(long)(t + 2) * N_ * G_];

        float a0 = 0.f, a1 = 0.f, a2 = 0.f, a3 = 0.f;
        const float4* h4 = (const float4*)hS;
        #define DOT4(i)                            \
            {                                      \
                float4 hv = h4[i];                 \
                a0 = fmaf(w##i[0], hv.x, a0);      \
                a1 = fmaf(w##i[1], hv.y, a1);      \
                a2 = fmaf(w##i[2], hv.z, a2);      \
                a3 = fmaf(w##i[3], hv.w, a3);      \
            }
        DOT4(0)  DOT4(1)  DOT4(2)  DOT4(3)
        DOT4(4)  DOT4(5)  DOT4(6)  DOT4(7)
        DOT4(8)  DOT4(9)  DOT4(10) DOT4(11)
        DOT4(12) DOT4(13) DOT4(14) DOT4(15)
        #undef DOT4
        gate += (a0 + a1) + (a2 + a3);

        gbuf[w][lane] = gate;
        __syncthreads();               // B1: gates visible
        if (w == 0) {
            float iv = fast_sig(gate);           // own gate == i
            float fv = fast_sig(gbuf[1][lane]);
            float gv = fast_tanh(gbuf[2][lane]);
            float ov = fast_sig(gbuf[3][lane]);
            ccell = fmaf(fv, ccell, iv * gv);
            hlast = ov * fast_tanh(ccell);
            hS[lane] = hlast;
        }
        __syncthreads();               // B2: new h visible
    }

    if (w == 0) {
        float p = hlast * W_fc[lane];
        #pragma unroll
        for (int m = 1; m < 64; m <<= 1) p += __shfl_xor(p, m);
        if (lane == 0) out[n] = p + b_fc[0];
    }
}

// ---------------------------------------------------------------------------
extern "C" void kernel_launch(void* const* d_in, const int* in_sizes, int n_in,
                              void* d_out, int out_size, void* d_ws, size_t ws_size,
                              hipStream_t stream) {
    const float* x     = (const float*)d_in[0];
    const float* A     = (const float*)d_in[1];
    const float* W_gcn = (const float*)d_in[2];
    const float* b_gcn = (const float*)d_in[3];
    const float* W_ih  = (const float*)d_in[4];
    const float* W_hh  = (const float*)d_in[5];
    const float* b_ih  = (const float*)d_in[6];
    const float* b_hh  = (const float*)d_in[7];
    const float* W_fc  = (const float*)d_in[8];
    const float* b_fc  = (const float*)d_in[9];
    float* out = (float*)d_out;
    float* ws  = (float*)d_ws;

    // 1) fused: copy A->out, a[k][v], sa[k]
    prep_kernel<<<NCOPY + K_, 256, 0, stream>>>(A, out, ws);
    // 2) tiled xa (one block per (n, ci, 64-t chunk))
    xa_kernel<<<N_ * CIN_ * (T_ / TT), 256, 0, stream>>>(x, ws);
    // 3) fused seq + input-side gate GEMM (one block per t)
    seqgates_kernel<<<T_, 256, 0, stream>>>(W_gcn, b_gcn, W_ih, b_ih, b_hh, ws);
    // 4) sequential LSTM scan + final FC (measured optimum)
    lstm_kernel<<<N_, 256, 0, stream>>>(W_hh, W_fc, b_fc, ws, out);
}